// Round 6
// baseline (342.788 us; speedup 1.0000x reference)
//
#include <hip/hip_runtime.h>
#include <stdint.h>

#define N_NODES 50000
#define N_EDGES 800000
#define M_PAD   50048   // 391 * 128
#define NREP    4       // counter replicas
#define RCAP    32      // per-replica bucket capacity (ushort) = 64B = 1 line
#define CSTR    50048   // cnt replica stride

typedef __attribute__((ext_vector_type(8))) short bf16x8;
typedef __attribute__((ext_vector_type(4))) float f32x4;

__device__ __forceinline__ unsigned short f2b(float f){
    unsigned int u = __builtin_bit_cast(unsigned int, f);
    u += 0x7fffu + ((u >> 16) & 1u);   // RNE
    return (unsigned short)(u >> 16);
}
__device__ __forceinline__ float b2f(unsigned short s){
    unsigned int u = ((unsigned int)s) << 16;
    return __builtin_bit_cast(float, u);
}

__device__ __forceinline__ void gl_lds16(const void* g, void* l){
    __builtin_amdgcn_global_load_lds(
        (const __attribute__((address_space(1))) void*)g,
        (__attribute__((address_space(3))) void*)l, 16, 0, 0);
}

// ---------------- x -> bf16 (padded) + zero cnt, one pass ----------------
__global__ void k_x2b(const float* __restrict__ x, unsigned short* __restrict__ xb,
                      int* __restrict__ cnt){
    int gi = blockIdx.x * 256 + threadIdx.x;
    if (gi < NREP * CSTR) cnt[gi] = 0;
    size_t e0 = (size_t)gi * 8;                     // 8 elems/thread, rows are 128 -> no straddle
    if (e0 >= (size_t)M_PAD * 128) return;
    bf16x8 o;
    if ((e0 >> 7) < N_NODES){
        const float4* xp = (const float4*)(x + e0);
        float4 a = xp[0], b = xp[1];
        o[0] = (short)f2b(a.x); o[1] = (short)f2b(a.y);
        o[2] = (short)f2b(a.z); o[3] = (short)f2b(a.w);
        o[4] = (short)f2b(b.x); o[5] = (short)f2b(b.y);
        o[6] = (short)f2b(b.z); o[7] = (short)f2b(b.w);
    } else {
#pragma unroll
        for (int i = 0; i < 8; ++i) o[i] = 0;
    }
    *(bf16x8*)(xb + e0) = o;
}

// ---------------- replicated bucket-CSR scatter ----------------
// replica r = tid&3; cnt[r*CSTR+d] on distinct lines per replica (contention /4);
// bucket (d,r) = 32 ushorts = exactly one 64B line.
__global__ void k_scatter(const int* __restrict__ ei, int* __restrict__ cnt,
                          unsigned short* __restrict__ csr){
    int e = blockIdx.x * 256 + threadIdx.x;
    if (e < N_EDGES){
        unsigned d = (unsigned)ei[N_EDGES + e];
        unsigned s = (unsigned)ei[e];
        if (d < N_NODES && s < N_NODES){
            int r = threadIdx.x & 3;
            int p = atomicAdd(&cnt[r * CSTR + d], 1);
            if (p < RCAP) csr[(((d << 2) + r) << 5) + p] = (unsigned short)s;
        }
    }
}

// ---------------- aggregation ----------------
// conv1: bf16 input, C=128 (16 lanes x bf16x8 per row). Each wave-quarter owns
// one replica sublist; 4-deep unroll within -> up to 16 gathers in flight/wave.
__global__ __launch_bounds__(256) void k_agg1(const unsigned short* __restrict__ xb,
        const int* __restrict__ cnt, const unsigned short* __restrict__ csr,
        unsigned short* __restrict__ out){
    const int wave = threadIdx.x >> 6, lane = threadIdx.x & 63;
    const int quarter = lane >> 4, q = lane & 15;
    const int n = blockIdx.x * 4 + wave;
    if (n >= M_PAD) return;

    float a[8];
#pragma unroll
    for (int i = 0; i < 8; ++i) a[i] = 0.f;

    if (n < N_NODES){
        const bf16x8* xr = (const bf16x8*)xb;     // row stride 16
        if (quarter == 0){
            bf16x8 s = xr[(size_t)n * 16 + q];
#pragma unroll
            for (int i = 0; i < 8; ++i) a[i] = b2f((unsigned short)s[i]);
        }
        int cr = cnt[quarter * CSTR + n];
        if (cr > RCAP) cr = RCAP;
        const int base = ((n << 2) + quarter) << 5;
        int k = 0;
        for (; k + 3 < cr; k += 4){
            int j0 = csr[base + k], j1 = csr[base + k + 1];
            int j2 = csr[base + k + 2], j3 = csr[base + k + 3];
            bf16x8 v0 = xr[(size_t)j0 * 16 + q];
            bf16x8 v1 = xr[(size_t)j1 * 16 + q];
            bf16x8 v2 = xr[(size_t)j2 * 16 + q];
            bf16x8 v3 = xr[(size_t)j3 * 16 + q];
#pragma unroll
            for (int i = 0; i < 8; ++i)
                a[i] += (b2f((unsigned short)v0[i]) + b2f((unsigned short)v1[i]))
                      + (b2f((unsigned short)v2[i]) + b2f((unsigned short)v3[i]));
        }
        for (; k < cr; ++k){
            int j = csr[base + k];
            bf16x8 v = xr[(size_t)j * 16 + q];
#pragma unroll
            for (int i = 0; i < 8; ++i) a[i] += b2f((unsigned short)v[i]);
        }
#pragma unroll
        for (int i = 0; i < 8; ++i){
            a[i] += __shfl_xor(a[i], 16);
            a[i] += __shfl_xor(a[i], 32);
        }
    }
    if (quarter == 0){
        bf16x8 o;
#pragma unroll
        for (int i = 0; i < 8; ++i) o[i] = (short)f2b(a[i]);
        *(bf16x8*)&out[(size_t)n * 128 + q * 8] = o;   // pad rows -> zeros
    }
}

// conv2: bf16 input, C=256 (32 lanes x bf16x8). Each wave-half owns two
// replica sublists; 4-deep unroll within each.
__global__ __launch_bounds__(256) void k_agg2(const unsigned short* __restrict__ h,
        const int* __restrict__ cnt, const unsigned short* __restrict__ csr,
        unsigned short* __restrict__ out){
    const int wave = threadIdx.x >> 6, lane = threadIdx.x & 63;
    const int half = lane >> 5, q = lane & 31;
    const int n = blockIdx.x * 4 + wave;
    if (n >= M_PAD) return;

    float a[8];
#pragma unroll
    for (int i = 0; i < 8; ++i) a[i] = 0.f;

    if (n < N_NODES){
        const bf16x8* hr = (const bf16x8*)h;      // row stride 32
        if (half == 0){
            bf16x8 s = hr[(size_t)n * 32 + q];
#pragma unroll
            for (int i = 0; i < 8; ++i) a[i] = b2f((unsigned short)s[i]);
        }
#pragma unroll
        for (int rr = 0; rr < 2; ++rr){
            const int r = half * 2 + rr;
            int cr = cnt[r * CSTR + n];
            if (cr > RCAP) cr = RCAP;
            const int base = ((n << 2) + r) << 5;
            int k = 0;
            for (; k + 3 < cr; k += 4){
                int j0 = csr[base + k], j1 = csr[base + k + 1];
                int j2 = csr[base + k + 2], j3 = csr[base + k + 3];
                bf16x8 v0 = hr[(size_t)j0 * 32 + q];
                bf16x8 v1 = hr[(size_t)j1 * 32 + q];
                bf16x8 v2 = hr[(size_t)j2 * 32 + q];
                bf16x8 v3 = hr[(size_t)j3 * 32 + q];
#pragma unroll
                for (int i = 0; i < 8; ++i)
                    a[i] += (b2f((unsigned short)v0[i]) + b2f((unsigned short)v1[i]))
                          + (b2f((unsigned short)v2[i]) + b2f((unsigned short)v3[i]));
            }
            for (; k < cr; ++k){
                int j = csr[base + k];
                bf16x8 v = hr[(size_t)j * 32 + q];
#pragma unroll
                for (int i = 0; i < 8; ++i) a[i] += b2f((unsigned short)v[i]);
            }
        }
#pragma unroll
        for (int i = 0; i < 8; ++i) a[i] += __shfl_xor(a[i], 32);
    }
    if (half == 0){
        bf16x8 o;
#pragma unroll
        for (int i = 0; i < 8; ++i) o[i] = (short)f2b(a[i]);
        *(bf16x8*)&out[(size_t)n * 256 + q * 8] = o;   // pad rows -> zeros
    }
}

// ---------------- weight convert+transpose (all 6 in one launch) ----------------
__global__ void k_wt_all(const float* w0, const float* w1, const float* w2,
                         const float* w3, const float* w4, const float* w5,
                         unsigned short* o0, unsigned short* o1, unsigned short* o2,
                         unsigned short* o3, unsigned short* o4, unsigned short* o5){
    const int Ks[6]  = {128, 256, 256, 256, 256, 256};
    const int Ns[6]  = {256, 256, 256, 256, 256,  64};
    const int NPs[6] = {256, 256, 256, 256, 256, 128};
    int s = blockIdx.y;
    const float* w = (s == 0) ? w0 : (s == 1) ? w1 : (s == 2) ? w2
                   : (s == 3) ? w3 : (s == 4) ? w4 : w5;
    unsigned short* o = (s == 0) ? o0 : (s == 1) ? o1 : (s == 2) ? o2
                      : (s == 3) ? o3 : (s == 4) ? o4 : o5;
    int K = Ks[s], N = Ns[s], NP = NPs[s];
    int idx = blockIdx.x * 256 + threadIdx.x;
    if (idx >= NP * K) return;
    int np = idx / K, k = idx - np * K;
    float v = (np < N) ? w[(size_t)k * N + np] : 0.f;
    o[idx] = f2b(v);
}

// ---------------- GEMM (m97 structure, unchanged) ----------------
template<int K, int NOUT, bool RELU, bool BF16OUT>
__global__ __launch_bounds__(256) void k_gemm(const unsigned short* __restrict__ A,
        const unsigned short* __restrict__ WT, const float* __restrict__ bias,
        void* __restrict__ out, int mstore){
    __shared__ alignas(16) unsigned short As[128 * 32];
    __shared__ alignas(16) unsigned short Bs[128 * 32];
    const int tid  = threadIdx.x;
    const int lane = tid & 63;
    const int row0 = blockIdx.x * 128;
    const int col0 = blockIdx.y * 128;
    const int wm = (tid >> 6) >> 1, wn = (tid >> 6) & 1;

    const f32x4 fzero = {0.f, 0.f, 0.f, 0.f};
    f32x4 acc[4][4];
#pragma unroll
    for (int m = 0; m < 4; ++m)
#pragma unroll
        for (int n = 0; n < 4; ++n) acc[m][n] = fzero;

    const int o1 = tid * 16;
    const int o2 = 4096 + tid * 16;
    const char* Ab = (const char*)A;
    const char* Bb = (const char*)WT;

    for (int kt = 0; kt < K / 32; ++kt){
        const char* sA1 = Ab + ((size_t)(row0 + (o1 >> 6)) * K + kt * 32) * 2 + (o1 & 63);
        const char* sA2 = Ab + ((size_t)(row0 + (o2 >> 6)) * K + kt * 32) * 2 + (o2 & 63);
        const char* sB1 = Bb + ((size_t)(col0 + (o1 >> 6)) * K + kt * 32) * 2 + (o1 & 63);
        const char* sB2 = Bb + ((size_t)(col0 + (o2 >> 6)) * K + kt * 32) * 2 + (o2 & 63);
        gl_lds16(sA1, (char*)As + o1);
        gl_lds16(sA2, (char*)As + o2);
        gl_lds16(sB1, (char*)Bs + o1);
        gl_lds16(sB2, (char*)Bs + o2);
        __syncthreads();

        const int ar = wm * 64 + (lane & 15);
        const int bc = wn * 64 + (lane & 15);
        const int kk = (lane >> 4) * 8;
        bf16x8 bfrag[4];
#pragma unroll
        for (int n = 0; n < 4; ++n)
            bfrag[n] = *(const bf16x8*)&Bs[(bc + n * 16) * 32 + kk];
#pragma unroll
        for (int m = 0; m < 4; ++m){
            bf16x8 af = *(const bf16x8*)&As[(ar + m * 16) * 32 + kk];
#pragma unroll
            for (int n = 0; n < 4; ++n)
                acc[m][n] = __builtin_amdgcn_mfma_f32_16x16x32_bf16(af, bfrag[n], acc[m][n], 0, 0, 0);
        }
        __syncthreads();
    }

#pragma unroll
    for (int m = 0; m < 4; ++m){
        const int rb = row0 + wm * 64 + m * 16 + ((lane >> 4) << 2);
#pragma unroll
        for (int n = 0; n < 4; ++n){
            const int c = col0 + wn * 64 + n * 16 + (lane & 15);
            if (c < NOUT){
                const float bv = bias[c];
#pragma unroll
                for (int r = 0; r < 4; ++r){
                    const int row = rb + r;
                    if (row < mstore){
                        float v = acc[m][n][r] + bv;
                        if (RELU) v = fmaxf(v, 0.f);
                        if (BF16OUT)
                            ((unsigned short*)out)[(size_t)row * NOUT + c] = f2b(v);
                        else
                            ((float*)out)[(size_t)row * NOUT + c] = v;
                    }
                }
            }
        }
    }
}

// ---------------- launch ----------------
extern "C" void kernel_launch(void* const* d_in, const int* in_sizes, int n_in,
                              void* d_out, int out_size, void* d_ws, size_t ws_size,
                              hipStream_t stream){
    const float* x   = (const float*)d_in[0];
    const int*   ei  = (const int*)d_in[1];      // int32: [2][N_EDGES] flattened
    const float* w1a = (const float*)d_in[2];
    const float* b1a = (const float*)d_in[3];
    const float* w1b = (const float*)d_in[4];
    const float* b1b = (const float*)d_in[5];
    const float* w2a = (const float*)d_in[6];
    const float* b2a = (const float*)d_in[7];
    const float* w2b = (const float*)d_in[8];
    const float* b2b = (const float*)d_in[9];
    const float* w3a = (const float*)d_in[10];
    const float* b3a = (const float*)d_in[11];
    const float* w3b = (const float*)d_in[12];
    const float* b3b = (const float*)d_in[13];

    char* ws = (char*)d_ws;
    size_t off = 0;
    auto take = [&](size_t bytes) -> char* {
        off = (off + 255) & ~(size_t)255;
        char* p = ws + off;
        off += bytes;
        return p;
    };
    unsigned short* xb   = (unsigned short*)take((size_t)M_PAD * 128 * 2);
    unsigned short* big0 = (unsigned short*)take((size_t)M_PAD * 256 * 2);
    unsigned short* big1 = (unsigned short*)take((size_t)M_PAD * 256 * 2);
    unsigned short* big2 = (unsigned short*)take((size_t)M_PAD * 256 * 2);
    unsigned short* wt1a = (unsigned short*)take(256 * 128 * 2);
    unsigned short* wt1b = (unsigned short*)take(256 * 256 * 2);
    unsigned short* wt2a = (unsigned short*)take(256 * 256 * 2);
    unsigned short* wt2b = (unsigned short*)take(256 * 256 * 2);
    unsigned short* wt3a = (unsigned short*)take(256 * 256 * 2);
    unsigned short* wt3b = (unsigned short*)take(128 * 256 * 2);
    int*            cnt  = (int*)take((size_t)NREP * CSTR * 4);
    unsigned short* csr  = (unsigned short*)take((size_t)N_NODES * NREP * RCAP * 2);

    // x -> bf16 padded + zero cnt
    k_x2b<<<(M_PAD * 128 / 8 + 255) / 256, 256, 0, stream>>>(x, xb, cnt);
    // replicated bucket CSR
    k_scatter<<<(N_EDGES + 255) / 256, 256, 0, stream>>>(ei, cnt, csr);
    // weights -> bf16 transposed [N][K]
    k_wt_all<<<dim3(256, 6), 256, 0, stream>>>(w1a, w1b, w2a, w2b, w3a, w3b,
                                               wt1a, wt1b, wt2a, wt2b, wt3a, wt3b);

    // conv1
    k_agg1<<<M_PAD / 4, 256, 0, stream>>>(xb, cnt, csr, big0);
    k_gemm<128, 256, true,  true ><<<dim3(391, 2), 256, 0, stream>>>(big0, wt1a, b1a, big1, M_PAD);
    k_gemm<256, 256, true,  true ><<<dim3(391, 2), 256, 0, stream>>>(big1, wt1b, b1b, big2, M_PAD);
    // conv2
    k_agg2<<<M_PAD / 4, 256, 0, stream>>>(big2, cnt, csr, big0);
    k_gemm<256, 256, true,  true ><<<dim3(391, 2), 256, 0, stream>>>(big0, wt2a, b2a, big1, M_PAD);
    k_gemm<256, 256, true,  true ><<<dim3(391, 2), 256, 0, stream>>>(big1, wt2b, b2b, big0, M_PAD);
    // head
    k_gemm<256, 256, true,  true ><<<dim3(391, 2), 256, 0, stream>>>(big0, wt3a, b3a, big1, M_PAD);
    k_gemm<256,  64, false, false><<<dim3(391, 1), 256, 0, stream>>>(big1, wt3b, b3b, d_out, N_NODES);
}